// Round 3
// baseline (213.823 us; speedup 1.0000x reference)
//
#include <hip/hip_runtime.h>

// MFELoss: fused softmax(C=4) + masked-mean reduction to a scalar.
// R9 = R8 + 4-consecutive-row blocking for int4 target loads.
// Ledger: ~160us = 2 harness poison fills (immovable). ~41us controllable:
// mfe_partial (~33us vs 25us BW floor) + mfe_final (~4us) + gaps.
// Theory: main kernel is VMEM-issue-limited, not BW-limited. Old mapping
// issued 16 scalar-dword target loads/thread (256B/wave/inst). New mapping:
// each thread owns 4 consecutive rows per group -> 1 int4 target load per
// group. VMEM insts/thread 32 -> 20. Preds: 4x16B at 64B lane stride; the
// instruction quad covers a contiguous 4KB/wave span, so HBM line traffic
// is unchanged (L2 absorbs the quartering, nt = evict-first not bypass).
// Unchanged from R8 (proven 201.2us): 512x1024 grid, register double-buffer
// with sched_barrier pin, nt loads, block-double partials (12KB handoff),
// 512-thread final kernel.

#define BLOCK 1024
#define GROUPS 4            // groups per thread
#define RPG 4               // consecutive rows per group
#define WAVES (BLOCK / 64)

typedef float vfloat4 __attribute__((ext_vector_type(4)));
typedef int   vint4   __attribute__((ext_vector_type(4)));

__device__ __forceinline__ void mfe_row(vfloat4 x, int t, int o,
                                        float& fne_acc, float& fpe_acc,
                                        float& cnt_acc) {
    float m = fmaxf(fmaxf(x.x, x.y), fmaxf(x.z, x.w));
    float e0 = __expf(x.x - m);
    float e1 = __expf(x.y - m);
    float e2 = __expf(x.z - m);
    float e3 = __expf(x.w - m);
    float S = (e0 + e1) + (e2 + e3);
    float r = 1.0f / S;
    float p0 = e0 * r, p1 = e1 * r, p2 = e2 * r, p3 = e3 * r;
    float s = ((p0 + p1) + p2) + p3;          // ~1.0, computed faithfully
    float po = (o == 0) ? p0 : (o == 1) ? p1 : (o == 2) ? p2 : p3;

    float d1 = s - po;
    float d2 = po - 1.0f;
    float fne_i = 0.5f * (d1 * d1 + d2 * d2);
    float fpe_i = po * po;                    // 0.5*(po^2+po^2)

    bool is_o = (t == o);
    fne_acc += is_o ? fne_i : 0.0f;
    fpe_acc += is_o ? 0.0f : fpe_i;
    cnt_acc += is_o ? 1.0f : 0.0f;            // exact in fp32 at these counts
}

__global__ __launch_bounds__(BLOCK) void mfe_partial(
    const vfloat4* __restrict__ preds,
    const int* __restrict__ target,
    const int* __restrict__ others_idx_p,
    double* __restrict__ fne_b,
    double* __restrict__ fpe_b,
    double* __restrict__ cnt_b,
    int n_rows)
{
    const int o = *others_idx_p;  // wave-uniform scalar
    int tid = blockIdx.x * BLOCK + threadIdx.x;
    int nth = gridDim.x * BLOCK;
    const vint4* __restrict__ target4 = (const vint4*)target;

    float fne_acc = 0.0f, fpe_acc = 0.0f, cnt_acc = 0.0f;

    // fast path: this thread's last group is fully in-bounds and int4-aligned
    if ((tid + (GROUPS - 1) * nth + 1) * RPG <= n_rows) {
        vfloat4 xbuf[2][RPG];
        vint4   tbuf[2];

        // prologue: fill buffer 0 (group 0: rows 4*tid .. 4*tid+3)
        #pragma unroll
        for (int j = 0; j < RPG; ++j)
            xbuf[0][j] = __builtin_nontemporal_load(&preds[RPG * tid + j]);
        tbuf[0] = __builtin_nontemporal_load(&target4[tid]);

        #pragma unroll
        for (int g = 0; g < GROUPS; ++g) {
            int cur = g & 1;
            int nxt = cur ^ 1;
            // prefetch next group before touching current one
            if (g + 1 < GROUPS) {
                int pbase = RPG * (tid + (g + 1) * nth);
                #pragma unroll
                for (int j = 0; j < RPG; ++j)
                    xbuf[nxt][j] = __builtin_nontemporal_load(&preds[pbase + j]);
                tbuf[nxt] = __builtin_nontemporal_load(&target4[tid + (g + 1) * nth]);
            }
            // pin prefetch issue before compute
            __builtin_amdgcn_sched_barrier(0);
            #pragma unroll
            for (int j = 0; j < RPG; ++j)
                mfe_row(xbuf[cur][j], tbuf[cur][j], o,
                        fne_acc, fpe_acc, cnt_acc);
        }
    } else {
        for (int i = tid; i < n_rows; i += nth)
            mfe_row(preds[i], target[i], o, fne_acc, fpe_acc, cnt_acc);
    }

    // 64-lane wave reduction (fp32)
    #pragma unroll
    for (int off = 32; off > 0; off >>= 1) {
        fne_acc += __shfl_down(fne_acc, off, 64);
        fpe_acc += __shfl_down(fpe_acc, off, 64);
        cnt_acc += __shfl_down(cnt_acc, off, 64);
    }

    // block reduction in double -> one partial triple per block (12KB total)
    __shared__ double s_fn[WAVES], s_fp[WAVES], s_c[WAVES];
    int wave = threadIdx.x >> 6;
    int lane = threadIdx.x & 63;
    if (lane == 0) {
        s_fn[wave] = (double)fne_acc;
        s_fp[wave] = (double)fpe_acc;
        s_c[wave]  = (double)cnt_acc;
    }
    __syncthreads();
    if (threadIdx.x == 0) {
        double fn = 0.0, fp = 0.0, c = 0.0;
        #pragma unroll
        for (int w = 0; w < WAVES; ++w) { fn += s_fn[w]; fp += s_fp[w]; c += s_c[w]; }
        fne_b[blockIdx.x] = fn;
        fpe_b[blockIdx.x] = fp;
        cnt_b[blockIdx.x] = c;
        // visibility to mfe_final: implicit end-of-kernel release + stream order
    }
}

__global__ __launch_bounds__(512) void mfe_final(
    const double* __restrict__ fne_b,
    const double* __restrict__ fpe_b,
    const double* __restrict__ cnt_b,
    int nblocks, int n_rows, float* __restrict__ out)
{
    double fn = 0.0, fp = 0.0, c = 0.0;
    for (int i = threadIdx.x; i < nblocks; i += 512) {
        fn += fne_b[i];
        fp += fpe_b[i];
        c  += cnt_b[i];
    }
    #pragma unroll
    for (int off = 32; off > 0; off >>= 1) {
        fn += __shfl_down(fn, off, 64);
        fp += __shfl_down(fp, off, 64);
        c  += __shfl_down(c, off, 64);
    }
    __shared__ double s_fn[8], s_fp[8], s_c[8];
    int wave = threadIdx.x >> 6;
    int lane = threadIdx.x & 63;
    if (lane == 0) { s_fn[wave] = fn; s_fp[wave] = fp; s_c[wave] = c; }
    __syncthreads();

    if (threadIdx.x == 0) {
        double tfn = 0.0, tfp = 0.0, tc = 0.0;
        #pragma unroll
        for (int w = 0; w < 8; ++w) { tfn += s_fn[w]; tfp += s_fp[w]; tc += s_c[w]; }
        double fne_num = tc;
        double fpe_num = (double)n_rows - tc;
        double res = 0.0;
        if (fpe_num > 0.0) res += tfp / fpe_num;
        if (fne_num > 0.0) res += tfn / fne_num;
        out[0] = (float)res;
    }
}

extern "C" void kernel_launch(void* const* d_in, const int* in_sizes, int n_in,
                              void* d_out, int out_size, void* d_ws, size_t ws_size,
                              hipStream_t stream) {
    const vfloat4* preds = (const vfloat4*)d_in[0];
    const int* target = (const int*)d_in[1];
    const int* others_idx = (const int*)d_in[2];
    float* out = (float*)d_out;

    int n_rows = in_sizes[0] / 4;   // B = 8388608 (vfloat4 rows)

    int grid = 512;                 // 16 rows/thread * 1024 thr * 512 = 2^23

    double* fne_b = (double*)d_ws;
    double* fpe_b = fne_b + grid;
    double* cnt_b = fpe_b + grid;

    mfe_partial<<<grid, BLOCK, 0, stream>>>(preds, target, others_idx,
                                            fne_b, fpe_b, cnt_b, n_rows);
    mfe_final<<<1, 512, 0, stream>>>(fne_b, fpe_b, cnt_b, grid, n_rows, out);
}

// Round 4
// 205.842 us; speedup vs baseline: 1.0388x; 1.0388x over previous
//
#include <hip/hip_runtime.h>

// MFELoss: fused softmax(C=4) + masked-mean reduction to a scalar.
// R10 = R8 revert + LDS-staged int4 target loads (clean single-variable
// test of R9's "VMEM-issue-limited" hypothesis).
// R9 LESSON: giving each lane 4 consecutive rows broke preds coalescing
// (64B lane stride -> 4x line requests/instruction) and cost +12.6us.
// Here the preds stream is byte-identical to R8 (lane-stride 16B,
// double-buffered, nontemporal). Only the target path changes: per
// iteration a block consumes a contiguous 4KB target span, so stage all
// 16 spans (64KB) into LDS upfront via 4 coalesced int4 loads/thread +
// one __syncthreads, then read per-row targets from LDS (conflict-free,
// lane-stride 4B). VMEM insts/thread: 32 -> 20, preds pattern untouched.
// LDS 64.4KB/block -> exactly 2 blocks/CU (grid 512 stays co-resident).
// If this lands within noise of 201.2us, the kernel is HBM-BW-bound and
// the remaining gap is fixed overhead -> roofline.
// ~157-160us of dur_us is fixed harness poison-fill overhead (2 x ~79us).

#define BLOCK 1024
#define ROWS 16
#define CHUNK 4
#define STAGES (ROWS / CHUNK)
#define WAVES (BLOCK / 64)

typedef float vfloat4 __attribute__((ext_vector_type(4)));
typedef int   vint4   __attribute__((ext_vector_type(4)));

__device__ __forceinline__ void mfe_row(vfloat4 x, int t, int o,
                                        float& fne_acc, float& fpe_acc,
                                        float& cnt_acc) {
    float m = fmaxf(fmaxf(x.x, x.y), fmaxf(x.z, x.w));
    float e0 = __expf(x.x - m);
    float e1 = __expf(x.y - m);
    float e2 = __expf(x.z - m);
    float e3 = __expf(x.w - m);
    float S = (e0 + e1) + (e2 + e3);
    float r = 1.0f / S;
    float p0 = e0 * r, p1 = e1 * r, p2 = e2 * r, p3 = e3 * r;
    float s = ((p0 + p1) + p2) + p3;          // ~1.0, computed faithfully
    float po = (o == 0) ? p0 : (o == 1) ? p1 : (o == 2) ? p2 : p3;

    float d1 = s - po;
    float d2 = po - 1.0f;
    float fne_i = 0.5f * (d1 * d1 + d2 * d2);
    float fpe_i = po * po;                    // 0.5*(po^2+po^2)

    bool is_o = (t == o);
    fne_acc += is_o ? fne_i : 0.0f;
    fpe_acc += is_o ? 0.0f : fpe_i;
    cnt_acc += is_o ? 1.0f : 0.0f;            // exact in fp32 at these counts
}

__global__ __launch_bounds__(BLOCK) void mfe_partial(
    const vfloat4* __restrict__ preds,
    const int* __restrict__ target,
    const int* __restrict__ others_idx_p,
    double* __restrict__ fne_b,
    double* __restrict__ fpe_b,
    double* __restrict__ cnt_b,
    int n_rows)
{
    const int o = *others_idx_p;  // wave-uniform scalar
    int tid = blockIdx.x * BLOCK + threadIdx.x;
    int nth = gridDim.x * BLOCK;

    // 16 iterations x 1024 contiguous targets per block = 64KB
    __shared__ int lds_t[ROWS * BLOCK];

    float fne_acc = 0.0f, fpe_acc = 0.0f, cnt_acc = 0.0f;

    // block-uniform fast-path guard: block's largest row in bounds
    int block_last = blockIdx.x * BLOCK + (BLOCK - 1) + (ROWS - 1) * nth;
    if (block_last < n_rows) {
        // ---- stage all targets for this block: 4 coalesced int4/thread ----
        // int4-linear id v in [0,4096): span = v>>8 (256 int4 per 1024-row
        // span), within-span = v&255. Global int4 index:
        //   blockIdx*256 + span*(nth/4) + within
        const vint4* __restrict__ target4 = (const vint4*)target;
        #pragma unroll
        for (int sIt = 0; sIt < 4; ++sIt) {
            int v = sIt * BLOCK + threadIdx.x;
            int span = v >> 8;
            int within = v & 255;
            vint4 t4 = __builtin_nontemporal_load(
                &target4[blockIdx.x * 256 + span * (nth >> 2) + within]);
            ((vint4*)lds_t)[v] = t4;
        }

        vfloat4 xbuf[2][CHUNK];

        // preds prologue: fill buffer 0 (issued before the staging barrier
        // so the HBM round-trips overlap)
        #pragma unroll
        for (int k = 0; k < CHUNK; ++k) {
            int i = tid + k * nth;
            xbuf[0][k] = __builtin_nontemporal_load(&preds[i]);
        }

        __syncthreads();   // staged targets visible

        #pragma unroll
        for (int s = 0; s < STAGES; ++s) {
            int cur = s & 1;
            int nxt = cur ^ 1;
            // prefetch next preds chunk before touching current one
            if (s + 1 < STAGES) {
                #pragma unroll
                for (int k = 0; k < CHUNK; ++k) {
                    int i = tid + ((s + 1) * CHUNK + k) * nth;
                    xbuf[nxt][k] = __builtin_nontemporal_load(&preds[i]);
                }
            }
            // pin prefetch issue before compute
            __builtin_amdgcn_sched_barrier(0);
            #pragma unroll
            for (int k = 0; k < CHUNK; ++k) {
                int t = lds_t[(s * CHUNK + k) * BLOCK + threadIdx.x];
                mfe_row(xbuf[cur][k], t, o, fne_acc, fpe_acc, cnt_acc);
            }
        }
    } else {
        for (int i = tid; i < n_rows; i += nth)
            mfe_row(preds[i], target[i], o, fne_acc, fpe_acc, cnt_acc);
    }

    // 64-lane wave reduction (fp32)
    #pragma unroll
    for (int off = 32; off > 0; off >>= 1) {
        fne_acc += __shfl_down(fne_acc, off, 64);
        fpe_acc += __shfl_down(fpe_acc, off, 64);
        cnt_acc += __shfl_down(cnt_acc, off, 64);
    }

    // block reduction in double -> one partial triple per block (12KB total)
    __shared__ double s_fn[WAVES], s_fp[WAVES], s_c[WAVES];
    int wave = threadIdx.x >> 6;
    int lane = threadIdx.x & 63;
    if (lane == 0) {
        s_fn[wave] = (double)fne_acc;
        s_fp[wave] = (double)fpe_acc;
        s_c[wave]  = (double)cnt_acc;
    }
    __syncthreads();
    if (threadIdx.x == 0) {
        double fn = 0.0, fp = 0.0, c = 0.0;
        #pragma unroll
        for (int w = 0; w < WAVES; ++w) { fn += s_fn[w]; fp += s_fp[w]; c += s_c[w]; }
        fne_b[blockIdx.x] = fn;
        fpe_b[blockIdx.x] = fp;
        cnt_b[blockIdx.x] = c;
        // visibility to mfe_final: implicit end-of-kernel release + stream order
    }
}

__global__ __launch_bounds__(512) void mfe_final(
    const double* __restrict__ fne_b,
    const double* __restrict__ fpe_b,
    const double* __restrict__ cnt_b,
    int nblocks, int n_rows, float* __restrict__ out)
{
    double fn = 0.0, fp = 0.0, c = 0.0;
    for (int i = threadIdx.x; i < nblocks; i += 512) {
        fn += fne_b[i];
        fp += fpe_b[i];
        c  += cnt_b[i];
    }
    #pragma unroll
    for (int off = 32; off > 0; off >>= 1) {
        fn += __shfl_down(fn, off, 64);
        fp += __shfl_down(fp, off, 64);
        c  += __shfl_down(c, off, 64);
    }
    __shared__ double s_fn[8], s_fp[8], s_c[8];
    int wave = threadIdx.x >> 6;
    int lane = threadIdx.x & 63;
    if (lane == 0) { s_fn[wave] = fn; s_fp[wave] = fp; s_c[wave] = c; }
    __syncthreads();

    if (threadIdx.x == 0) {
        double tfn = 0.0, tfp = 0.0, tc = 0.0;
        #pragma unroll
        for (int w = 0; w < 8; ++w) { tfn += s_fn[w]; tfp += s_fp[w]; tc += s_c[w]; }
        double fne_num = tc;
        double fpe_num = (double)n_rows - tc;
        double res = 0.0;
        if (fpe_num > 0.0) res += tfp / fpe_num;
        if (fne_num > 0.0) res += tfn / fne_num;
        out[0] = (float)res;
    }
}

extern "C" void kernel_launch(void* const* d_in, const int* in_sizes, int n_in,
                              void* d_out, int out_size, void* d_ws, size_t ws_size,
                              hipStream_t stream) {
    const vfloat4* preds = (const vfloat4*)d_in[0];
    const int* target = (const int*)d_in[1];
    const int* others_idx = (const int*)d_in[2];
    float* out = (float*)d_out;

    int n_rows = in_sizes[0] / 4;   // B = 8388608 (vfloat4 rows)

    int grid = (n_rows + BLOCK * ROWS - 1) / (BLOCK * ROWS);  // 512 for B=2^23

    double* fne_b = (double*)d_ws;
    double* fpe_b = fne_b + grid;
    double* cnt_b = fpe_b + grid;

    mfe_partial<<<grid, BLOCK, 0, stream>>>(preds, target, others_idx,
                                            fne_b, fpe_b, cnt_b, n_rows);
    mfe_final<<<1, 512, 0, stream>>>(fne_b, fpe_b, cnt_b, grid, n_rows, out);
}

// Round 5
// 202.759 us; speedup vs baseline: 1.0546x; 1.0152x over previous
//
#include <hip/hip_runtime.h>

// MFELoss: fused softmax(C=4) + masked-mean reduction to a scalar.
// R11 = exact revert to R8 (proven best, 201.2us) after the diagnostic
// rounds refuted every remaining lever:
//  - R7: single-kernel ticket fusion        -> +17us (512 per-block fences;
//        kernel boundary is the cheapest device-scope fence on gfx950)
//  - R9: consecutive-row int4 target loads  -> +12.6us (broke preds
//        coalescing: 64B lane stride = 4x line requests/instruction)
//  - R10: LDS-staged targets, preds untouched -> +4.6us (VMEM issue count
//        was never the bottleneck; upfront stage burst + barrier cost)
// Conclusion: mfe_partial is HBM-BW-bound. Ledger: ~157us fixed harness
// poison fills (2 x 512MiB @ ~6.8TB/s) + ~26.6us partial BW floor
// (167.8MB @ 6.3TB/s) + ~3us final + launch gaps ~= 192-196us ideal vs
// 201.2 measured -> within a few percent of the composed roofline.
// Structure: 512 blocks x 1024 thr (exact 2 blocks/CU co-resident),
// register double-buffer (prefetch chunk s+1 before computing chunk s),
// nontemporal loads, fp32 wave reduce -> double block partial (12KB
// handoff) -> 512-thread final kernel.

#define BLOCK 1024
#define ROWS 16
#define CHUNK 4
#define STAGES (ROWS / CHUNK)
#define WAVES (BLOCK / 64)

typedef float vfloat4 __attribute__((ext_vector_type(4)));

__device__ __forceinline__ void mfe_row(vfloat4 x, int t, int o,
                                        float& fne_acc, float& fpe_acc,
                                        float& cnt_acc) {
    float m = fmaxf(fmaxf(x.x, x.y), fmaxf(x.z, x.w));
    float e0 = __expf(x.x - m);
    float e1 = __expf(x.y - m);
    float e2 = __expf(x.z - m);
    float e3 = __expf(x.w - m);
    float S = (e0 + e1) + (e2 + e3);
    float r = 1.0f / S;
    float p0 = e0 * r, p1 = e1 * r, p2 = e2 * r, p3 = e3 * r;
    float s = ((p0 + p1) + p2) + p3;          // ~1.0, computed faithfully
    float po = (o == 0) ? p0 : (o == 1) ? p1 : (o == 2) ? p2 : p3;

    float d1 = s - po;
    float d2 = po - 1.0f;
    float fne_i = 0.5f * (d1 * d1 + d2 * d2);
    float fpe_i = po * po;                    // 0.5*(po^2+po^2)

    bool is_o = (t == o);
    fne_acc += is_o ? fne_i : 0.0f;
    fpe_acc += is_o ? 0.0f : fpe_i;
    cnt_acc += is_o ? 1.0f : 0.0f;            // exact in fp32 at these counts
}

__global__ __launch_bounds__(BLOCK) void mfe_partial(
    const vfloat4* __restrict__ preds,
    const int* __restrict__ target,
    const int* __restrict__ others_idx_p,
    double* __restrict__ fne_b,
    double* __restrict__ fpe_b,
    double* __restrict__ cnt_b,
    int n_rows)
{
    const int o = *others_idx_p;  // wave-uniform scalar
    int tid = blockIdx.x * BLOCK + threadIdx.x;
    int nth = gridDim.x * BLOCK;

    float fne_acc = 0.0f, fpe_acc = 0.0f, cnt_acc = 0.0f;

    if (tid + (ROWS - 1) * nth < n_rows) {
        vfloat4 xbuf[2][CHUNK];
        int     tbuf[2][CHUNK];

        // prologue: fill buffer 0
        #pragma unroll
        for (int k = 0; k < CHUNK; ++k) {
            int i = tid + k * nth;
            xbuf[0][k] = __builtin_nontemporal_load(&preds[i]);
            tbuf[0][k] = __builtin_nontemporal_load(&target[i]);
        }

        #pragma unroll
        for (int s = 0; s < STAGES; ++s) {
            int cur = s & 1;
            int nxt = cur ^ 1;
            // prefetch next chunk before touching current one
            if (s + 1 < STAGES) {
                #pragma unroll
                for (int k = 0; k < CHUNK; ++k) {
                    int i = tid + ((s + 1) * CHUNK + k) * nth;
                    xbuf[nxt][k] = __builtin_nontemporal_load(&preds[i]);
                    tbuf[nxt][k] = __builtin_nontemporal_load(&target[i]);
                }
            }
            // pin prefetch issue before compute
            __builtin_amdgcn_sched_barrier(0);
            #pragma unroll
            for (int k = 0; k < CHUNK; ++k)
                mfe_row(xbuf[cur][k], tbuf[cur][k], o, fne_acc, fpe_acc, cnt_acc);
        }
    } else {
        for (int i = tid; i < n_rows; i += nth)
            mfe_row(preds[i], target[i], o, fne_acc, fpe_acc, cnt_acc);
    }

    // 64-lane wave reduction (fp32)
    #pragma unroll
    for (int off = 32; off > 0; off >>= 1) {
        fne_acc += __shfl_down(fne_acc, off, 64);
        fpe_acc += __shfl_down(fpe_acc, off, 64);
        cnt_acc += __shfl_down(cnt_acc, off, 64);
    }

    // block reduction in double -> one partial triple per block (12KB total)
    __shared__ double s_fn[WAVES], s_fp[WAVES], s_c[WAVES];
    int wave = threadIdx.x >> 6;
    int lane = threadIdx.x & 63;
    if (lane == 0) {
        s_fn[wave] = (double)fne_acc;
        s_fp[wave] = (double)fpe_acc;
        s_c[wave]  = (double)cnt_acc;
    }
    __syncthreads();
    if (threadIdx.x == 0) {
        double fn = 0.0, fp = 0.0, c = 0.0;
        #pragma unroll
        for (int w = 0; w < WAVES; ++w) { fn += s_fn[w]; fp += s_fp[w]; c += s_c[w]; }
        fne_b[blockIdx.x] = fn;
        fpe_b[blockIdx.x] = fp;
        cnt_b[blockIdx.x] = c;
        // visibility to mfe_final: implicit end-of-kernel release + stream order
    }
}

__global__ __launch_bounds__(512) void mfe_final(
    const double* __restrict__ fne_b,
    const double* __restrict__ fpe_b,
    const double* __restrict__ cnt_b,
    int nblocks, int n_rows, float* __restrict__ out)
{
    double fn = 0.0, fp = 0.0, c = 0.0;
    for (int i = threadIdx.x; i < nblocks; i += 512) {
        fn += fne_b[i];
        fp += fpe_b[i];
        c  += cnt_b[i];
    }
    #pragma unroll
    for (int off = 32; off > 0; off >>= 1) {
        fn += __shfl_down(fn, off, 64);
        fp += __shfl_down(fp, off, 64);
        c  += __shfl_down(c, off, 64);
    }
    __shared__ double s_fn[8], s_fp[8], s_c[8];
    int wave = threadIdx.x >> 6;
    int lane = threadIdx.x & 63;
    if (lane == 0) { s_fn[wave] = fn; s_fp[wave] = fp; s_c[wave] = c; }
    __syncthreads();

    if (threadIdx.x == 0) {
        double tfn = 0.0, tfp = 0.0, tc = 0.0;
        #pragma unroll
        for (int w = 0; w < 8; ++w) { tfn += s_fn[w]; tfp += s_fp[w]; tc += s_c[w]; }
        double fne_num = tc;
        double fpe_num = (double)n_rows - tc;
        double res = 0.0;
        if (fpe_num > 0.0) res += tfp / fpe_num;
        if (fne_num > 0.0) res += tfn / fne_num;
        out[0] = (float)res;
    }
}

extern "C" void kernel_launch(void* const* d_in, const int* in_sizes, int n_in,
                              void* d_out, int out_size, void* d_ws, size_t ws_size,
                              hipStream_t stream) {
    const vfloat4* preds = (const vfloat4*)d_in[0];
    const int* target = (const int*)d_in[1];
    const int* others_idx = (const int*)d_in[2];
    float* out = (float*)d_out;

    int n_rows = in_sizes[0] / 4;   // B = 8388608 (vfloat4 rows)

    int grid = (n_rows + BLOCK * ROWS - 1) / (BLOCK * ROWS);  // 512 for B=2^23

    double* fne_b = (double*)d_ws;
    double* fpe_b = fne_b + grid;
    double* cnt_b = fpe_b + grid;

    mfe_partial<<<grid, BLOCK, 0, stream>>>(preds, target, others_idx,
                                            fne_b, fpe_b, cnt_b, n_rows);
    mfe_final<<<1, 512, 0, stream>>>(fne_b, fpe_b, cnt_b, grid, n_rows, out);
}